// Round 1
// baseline (63.273 us; speedup 1.0000x reference)
//
#include <hip/hip_runtime.h>

// Sobel3D: data [4,1,256,256,64] f32 -> out [4,1,256,256,64] f32 (0/1).
// out = 1 iff >=2 of the 3 directional Sobel gradients are nonzero.
//
// Separable decomposition (cross-correlation, SAME zero padding):
//   per (d,h) row:  Srow = x[w-1]+2x[w]+x[w+1],  Drow = x[w-1]-x[w+1]
//   per plane d:    Dsum = Drow(h-1)+Drow(h)+Drow(h+1)
//                   Ssum = Srow(h-1)+Srow(h)+Srow(h+1)
//                   Sdif = Srow(h-1)-Srow(h+1)
//   Gx = Dsum(d-1)+2*Dsum(d)+Dsum(d+1)
//   Gy = Ssum(d-1)-Ssum(d+1)
//   Gz = Sdif(d-1)+Sdif(d)+Sdif(d+1)

constexpr int WW = 64;   // W dim == one wave
constexpr int HT = 8;    // output h-rows per block
constexpr int DC = 64;   // d-planes per block (march)
constexpr int NROWS = HT + 2;
constexpr int DDIM = 256;
constexpr int HDIM = 256;

__global__ __launch_bounds__(WW * HT) void sobel3d_kernel(
    const float* __restrict__ in, float* __restrict__ out) {
  const int w   = threadIdx.x;            // 0..63 (lane)
  const int y   = threadIdx.y;            // 0..HT-1
  const int tid = y * WW + w;
  const int h0  = blockIdx.x * HT;
  const int d0  = blockIdx.y * DC;
  const int b   = blockIdx.z;

  const size_t plane = (size_t)HDIM * WW;          // 16384
  const float* src = in  + (size_t)b * DDIM * plane;
  float*       dst = out + (size_t)b * DDIM * plane;

  // raw rows of one d-plane, with w-halo columns [0] and [WW+1] kept zero
  __shared__ float xs[NROWS][WW + 2];

  if (tid < NROWS) { xs[tid][0] = 0.f; xs[tid][WW + 1] = 0.f; }

  float pds = 0.f, pss = 0.f, psd = 0.f;   // plane d-1
  float cds = 0.f, css = 0.f, csd = 0.f;   // plane d
  float nds, nss, nsd;                     // plane d+1

  auto loadcompute = [&](int d, float& ods, float& oss, float& osd) {
    __syncthreads();   // previous compute done before overwriting xs
    #pragma unroll
    for (int e = tid; e < NROWS * WW; e += WW * HT) {
      const int r  = e >> 6;
      const int c  = e & 63;
      const int hr = h0 - 1 + r;
      float v = 0.f;
      if (hr >= 0 && hr < HDIM) {
        v = src[(size_t)d * plane + (size_t)hr * WW + c];
        v = (v == 255.f) ? 0.f : v;   // reference's where(data==255,0,data)
      }
      xs[r][c + 1] = v;
    }
    __syncthreads();
    // x[w-1]=xs[.][w], x[w]=xs[.][w+1], x[w+1]=xs[.][w+2]
    const float a0 = xs[y][w],     a1 = xs[y][w + 1],     a2 = xs[y][w + 2];
    const float b0 = xs[y + 1][w], b1 = xs[y + 1][w + 1], b2 = xs[y + 1][w + 2];
    const float c0 = xs[y + 2][w], c1 = xs[y + 2][w + 1], c2 = xs[y + 2][w + 2];
    const float Da = a0 - a2, Db = b0 - b2, Dc = c0 - c2;
    const float Sa = a0 + 2.f * a1 + a2;
    const float Sb = b0 + 2.f * b1 + b2;
    const float Sc = c0 + 2.f * c1 + c2;
    ods = Da + Db + Dc;   // Dsum
    oss = Sa + Sb + Sc;   // Ssum
    osd = Sa - Sc;        // Sdif
  };

  // prologue: plane d0-1 (zeros if OOB) and plane d0
  if (d0 > 0) loadcompute(d0 - 1, pds, pss, psd);
  loadcompute(d0, cds, css, csd);

  const int h = h0 + y;
  for (int d = d0; d < d0 + DC; ++d) {
    if (d + 1 < DDIM) {
      loadcompute(d + 1, nds, nss, nsd);
    } else {
      nds = 0.f; nss = 0.f; nsd = 0.f;
    }
    const float Gx = pds + 2.f * cds + nds;
    const float Gy = pss - nss;
    const float Gz = psd + csd + nsd;
    const int cnt = (Gx != 0.f) + (Gy != 0.f) + (Gz != 0.f);
    dst[(size_t)d * plane + (size_t)h * WW + w] = (cnt >= 2) ? 1.f : 0.f;
    pds = cds; pss = css; psd = csd;
    cds = nds; css = nss; csd = nsd;
  }
}

extern "C" void kernel_launch(void* const* d_in, const int* in_sizes, int n_in,
                              void* d_out, int out_size, void* d_ws, size_t ws_size,
                              hipStream_t stream) {
  const float* data = (const float*)d_in[0];
  // d_in[1] = Sobel weights — fixed by the reference, folded into the kernel.
  float* out = (float*)d_out;
  dim3 grid(HDIM / HT, DDIM / DC, 4);   // (32, 4, 4) = 512 blocks
  dim3 block(WW, HT);                   // 512 threads = 8 waves
  sobel3d_kernel<<<grid, block, 0, stream>>>(data, out);
}

// Round 2
// 40.967 us; speedup vs baseline: 1.5445x; 1.5445x over previous
//
#include <hip/hip_runtime.h>

// Sobel3D: data [4,1,256,256,64] f32 -> out [4,1,256,256,64] f32 (0/1).
// out = 1 iff >=2 of the 3 directional Sobel gradients are nonzero.
//
// Separable decomposition (cross-correlation, SAME zero padding):
//   per (d,h) row:  S[i] = x[i-1]+2x[i]+x[i+1],  D[i] = x[i-1]-x[i+1]
//   per plane d:    ds = D(h-1)+D(h)+D(h+1)
//                   ss = S(h-1)+S(h)+S(h+1)
//                   sd = S(h-1)-S(h+1)
//   Gx = ds(d-1)+2*ds(d)+ds(d+1)
//   Gy = ss(d-1)-ss(d+1)
//   Gz = sd(d-1)+sd(d)+sd(d+1)
//
// Design: NO LDS, NO barriers. Thread = (b, h, w0..w0+3), marches DC d-planes
// with a 3-plane register pipeline. h-halo = redundant row loads (L2/L3-hit);
// w-halo = 2 overlapping scalar loads (L1-hit). Pure streaming, deep load ILP.

constexpr int DDIM = 256;
constexpr int HDIM = 256;
constexpr int WWID = 64;
constexpr int DC   = 16;   // d-planes marched per thread

struct P3 { float ds[4], ss[4], sd[4]; };

__global__ __launch_bounds__(256) void sobel3d_kernel(
    const float* __restrict__ in, float* __restrict__ out) {
  const int lane = threadIdx.x;          // 0..63
  const int wg   = lane & 15;            // w-group within row
  const int hs   = lane >> 4;            // h-sub within wave
  const int w0   = wg * 4;
  const int h    = blockIdx.x * 16 + threadIdx.y * 4 + hs;
  const int d0   = blockIdx.y * DC;
  const int b    = blockIdx.z;

  const size_t plane = (size_t)HDIM * WWID;   // 16384 floats
  const float* src = in  + (size_t)b * DDIM * plane;
  float*       dst = out + (size_t)b * DDIM * plane;

  // load one w-window (6 values incl. halo) of row hr in plane d
  auto loadrow = [&](int d, int hr, float* x) {
    if (hr >= 0 && hr < HDIM) {
      const float* row = src + (size_t)d * plane + (size_t)hr * WWID;
      const float4 v = *(const float4*)(row + w0);
      x[1] = v.x; x[2] = v.y; x[3] = v.z; x[4] = v.w;
      x[0] = (wg > 0)  ? row[w0 - 1] : 0.f;
      x[5] = (wg < 15) ? row[w0 + 4] : 0.f;
      #pragma unroll
      for (int i = 0; i < 6; ++i) x[i] = (x[i] == 255.f) ? 0.f : x[i];
    } else {
      #pragma unroll
      for (int i = 0; i < 6; ++i) x[i] = 0.f;
    }
  };

  auto zero = [](P3& o) {
    #pragma unroll
    for (int i = 0; i < 4; ++i) { o.ds[i] = 0.f; o.ss[i] = 0.f; o.sd[i] = 0.f; }
  };

  // compute plane-d partials for this thread's 4 outputs
  auto computePlane = [&](int d, P3& o) {
    float xa[6], xb[6], xc[6];
    loadrow(d, h - 1, xa);
    loadrow(d, h,     xb);
    loadrow(d, h + 1, xc);
    #pragma unroll
    for (int i = 0; i < 4; ++i) {
      const float SA = fmaf(2.f, xa[i + 1], xa[i]) + xa[i + 2];
      const float SB = fmaf(2.f, xb[i + 1], xb[i]) + xb[i + 2];
      const float SC = fmaf(2.f, xc[i + 1], xc[i]) + xc[i + 2];
      const float DA = xa[i] - xa[i + 2];
      const float DB = xb[i] - xb[i + 2];
      const float DD = xc[i] - xc[i + 2];
      o.ds[i] = DA + DB + DD;
      o.ss[i] = SA + SB + SC;
      o.sd[i] = SA - SC;
    }
  };

  P3 p, c, n;
  if (d0 > 0) computePlane(d0 - 1, p); else zero(p);
  computePlane(d0, c);

  for (int d = d0; d < d0 + DC; ++d) {
    if (d + 1 < DDIM) computePlane(d + 1, n); else zero(n);
    float4 o;
    #pragma unroll
    for (int i = 0; i < 4; ++i) {
      const float Gx = fmaf(2.f, c.ds[i], p.ds[i]) + n.ds[i];
      const float Gy = p.ss[i] - n.ss[i];
      const float Gz = p.sd[i] + c.sd[i] + n.sd[i];
      const int cnt = (Gx != 0.f) + (Gy != 0.f) + (Gz != 0.f);
      (&o.x)[i] = (cnt >= 2) ? 1.f : 0.f;
    }
    *(float4*)&dst[(size_t)d * plane + (size_t)h * WWID + w0] = o;
    p = c;
    c = n;
  }
}

extern "C" void kernel_launch(void* const* d_in, const int* in_sizes, int n_in,
                              void* d_out, int out_size, void* d_ws, size_t ws_size,
                              hipStream_t stream) {
  const float* data = (const float*)d_in[0];
  // d_in[1] = Sobel weights — fixed by the reference, folded into the kernel.
  float* out = (float*)d_out;
  dim3 grid(HDIM / 16, DDIM / DC, 4);   // (16, 16, 4) = 1024 blocks
  dim3 block(WWID, 4);                  // 256 threads = 4 waves
  sobel3d_kernel<<<grid, block, 0, stream>>>(data, out);
}

// Round 3
// 36.567 us; speedup vs baseline: 1.7303x; 1.1203x over previous
//
#include <hip/hip_runtime.h>

// Sobel3D: data [4,1,256,256,64] f32 -> out [4,1,256,256,64] f32 (0/1).
// out = 1 iff >=2 of the 3 directional Sobel gradients are nonzero.
//
// Separable decomposition (cross-correlation, SAME zero padding):
//   per (d,h) row:  S[i] = x[i-1]+2x[i]+x[i+1],  D[i] = x[i-1]-x[i+1]
//   per plane d:    ds = D(h-1)+D(h)+D(h+1), ss = S(h-1)+S(h)+S(h+1),
//                   sd = S(h-1)-S(h+1)
//   Gx = ds(d-1)+2*ds(d)+ds(d+1); Gy = ss(d-1)-ss(d+1); Gz = sd(d-1)+sd(d)+sd(d+1)
//
// R3 design: no LDS/barriers; thread owns (b,h,w0..w0+3), marches DC planes.
//  - w-halo via 2 lane-shuffles per row (ds_bpermute) instead of scalar loads
//    -> 3 float4 VMEM loads per plane-step (was 9).
//  - cross-iteration register double-buffer: loads for plane d+2 issued before
//    consuming plane d+1 -> counted vmcnt, loads in flight a full iteration.

constexpr int DDIM = 256;
constexpr int HDIM = 256;
constexpr int WWID = 64;
constexpr int DC   = 8;    // d-planes per block

struct Raw { float4 a, b, c; };              // rows h-1,h,h+1 of one plane
struct P3  { float ds[4], ss[4], sd[4]; };   // per-plane combined partials

__global__ __launch_bounds__(256) void sobel3d_kernel(
    const float* __restrict__ in, float* __restrict__ out) {
  const int lane = threadIdx.x;          // 0..63
  const int wg   = lane & 15;            // w-group within row
  const int hs   = lane >> 4;            // h-sub within wave
  const int w0   = wg * 4;
  const int h    = blockIdx.x * 16 + threadIdx.y * 4 + hs;
  const int d0   = blockIdx.y * DC;
  const int b    = blockIdx.z;

  const size_t plane = (size_t)HDIM * WWID;   // 16384 floats
  const float* src = in  + (size_t)b * DDIM * plane;
  float*       dst = out + (size_t)b * DDIM * plane;

  const int lm = (lane - 1) & 63;   // neighbor lanes for w-halo exchange
  const int lp = (lane + 1) & 63;

  auto loadrow = [&](int d, int hr) -> float4 {
    if ((unsigned)hr < (unsigned)HDIM)
      return *(const float4*)(src + (size_t)d * plane + (size_t)hr * WWID + w0);
    return float4{0.f, 0.f, 0.f, 0.f};
  };
  auto loadPlane = [&](int d, Raw& r) {
    r.a = loadrow(d, h - 1);
    r.b = loadrow(d, h);
    r.c = loadrow(d, h + 1);
  };

  // row partials S (1,2,1) and D (1,0,-1) at the 4 output w positions
  auto rowSD = [&](float4 v, float* S, float* D) {
    const float x1 = (v.x == 255.f) ? 0.f : v.x;   // reference where()
    const float x2 = (v.y == 255.f) ? 0.f : v.y;
    const float x3 = (v.z == 255.f) ? 0.f : v.z;
    const float x4 = (v.w == 255.f) ? 0.f : v.w;
    float xm = __shfl(x4, lm, 64); if (wg == 0)  xm = 0.f;  // x[w0-1]
    float xp = __shfl(x1, lp, 64); if (wg == 15) xp = 0.f;  // x[w0+4]
    const float x[6] = {xm, x1, x2, x3, x4, xp};
    #pragma unroll
    for (int i = 0; i < 4; ++i) {
      S[i] = fmaf(2.f, x[i + 1], x[i]) + x[i + 2];
      D[i] = x[i] - x[i + 2];
    }
  };

  auto partials = [&](const Raw& r, P3& o) {
    float Sa[4], Da[4], Sb[4], Db[4], Sc[4], Dc[4];
    rowSD(r.a, Sa, Da);
    rowSD(r.b, Sb, Db);
    rowSD(r.c, Sc, Dc);
    #pragma unroll
    for (int i = 0; i < 4; ++i) {
      o.ds[i] = Da[i] + Db[i] + Dc[i];
      o.ss[i] = Sa[i] + Sb[i] + Sc[i];
      o.sd[i] = Sa[i] - Sc[i];
    }
  };

  auto zero = [](P3& o) {
    #pragma unroll
    for (int i = 0; i < 4; ++i) { o.ds[i] = 0.f; o.ss[i] = 0.f; o.sd[i] = 0.f; }
  };

  P3 p, c, n;
  Raw ra, rb;

  // prologue
  if (d0 > 0) { loadPlane(d0 - 1, ra); partials(ra, p); } else zero(p);
  loadPlane(d0, ra);          // plane d0
  loadPlane(d0 + 1, rb);      // plane d0+1 (d0+1 <= 249 < DDIM always)
  partials(ra, c);

  // one pipelined step: prefetch plane d+2 into `fill`, consume `cons` (=d+1)
  auto step = [&](int d, const Raw& cons, Raw& fill) {
    if (d + 2 <= d0 + DC && d + 2 < DDIM) loadPlane(d + 2, fill);
    if (d + 1 < DDIM) partials(cons, n); else zero(n);
    float4 o;
    #pragma unroll
    for (int i = 0; i < 4; ++i) {
      const float Gx = fmaf(2.f, c.ds[i], p.ds[i]) + n.ds[i];
      const float Gy = p.ss[i] - n.ss[i];
      const float Gz = p.sd[i] + c.sd[i] + n.sd[i];
      const int cnt = (Gx != 0.f) + (Gy != 0.f) + (Gz != 0.f);
      (&o.x)[i] = (cnt >= 2) ? 1.f : 0.f;
    }
    *(float4*)(dst + (size_t)d * plane + (size_t)h * WWID + w0) = o;
    p = c; c = n;
  };

  #pragma unroll
  for (int dd = 0; dd < DC; dd += 2) {   // unroll-by-2 keeps buffer swap static
    step(d0 + dd,     rb, ra);
    step(d0 + dd + 1, ra, rb);
  }
}

extern "C" void kernel_launch(void* const* d_in, const int* in_sizes, int n_in,
                              void* d_out, int out_size, void* d_ws, size_t ws_size,
                              hipStream_t stream) {
  const float* data = (const float*)d_in[0];
  // d_in[1] = Sobel weights — fixed by the reference, folded into the kernel.
  float* out = (float*)d_out;
  dim3 grid(HDIM / 16, DDIM / DC, 4);   // (16, 32, 4) = 2048 blocks
  dim3 block(WWID, 4);                  // 256 threads = 4 waves
  sobel3d_kernel<<<grid, block, 0, stream>>>(data, out);
}

// Round 4
// 30.303 us; speedup vs baseline: 2.0880x; 1.2067x over previous
//
#include <hip/hip_runtime.h>

// Sobel3D: data [4,1,256,256,64] f32 -> out [4,1,256,256,64] f32 (0/1).
// out = 1 iff >=2 of the 3 directional Sobel gradients are nonzero.
//
// Separable decomposition (cross-correlation, SAME zero padding):
//   per (d,h) row:  S[i] = x[i-1]+2x[i]+x[i+1],  D[i] = x[i-1]-x[i+1]
//   per plane d:    ds = D(h-1)+D(h)+D(h+1), ss = S(h-1)+S(h)+S(h+1),
//                   sd = S(h-1)-S(h+1)
//   Gx = ds(d-1)+2*ds(d)+ds(d+1); Gy = ss(d-1)-ss(d+1); Gz = sd(d-1)+sd(d)+sd(d+1)
//
// R4 design:
//  - no LDS/barriers; thread owns (b,h,w0..w0+3), 4 output planes, unrolled.
//  - w-halo via DPP row_shr:1/row_shl:1 (16-lane rows == our w-groups);
//    bound_ctrl zero-fill gives the w=0/w=63 boundary zeros for free.
//  - static 3-buffer raw-plane ring, 2 planes of loads in flight at every
//    consume point (vmcnt(6)-style), fully unrolled schedule.
//  - 8192 blocks (2 waves each) ~ 3x resident capacity -> tail balancing.

constexpr int DDIM = 256;
constexpr int HDIM = 256;
constexpr int WWID = 64;
constexpr int DC   = 4;    // output d-planes per block
constexpr int HT   = 8;    // h rows per block (2 waves)

struct P3 { float ds[4], ss[4], sd[4]; };

__device__ __forceinline__ float dpp_up1(float v) {   // lane n <- lane n-1 (16-lane row), edge->0
  return __builtin_bit_cast(float, __builtin_amdgcn_update_dpp(
      0, __builtin_bit_cast(int, v), 0x111, 0xf, 0xf, true));  // row_shr:1
}
__device__ __forceinline__ float dpp_dn1(float v) {   // lane n <- lane n+1 (16-lane row), edge->0
  return __builtin_bit_cast(float, __builtin_amdgcn_update_dpp(
      0, __builtin_bit_cast(int, v), 0x101, 0xf, 0xf, true));  // row_shl:1
}

__global__ __launch_bounds__(128) void sobel3d_kernel(
    const float* __restrict__ in, float* __restrict__ out) {
  const int lane = threadIdx.x;          // 0..63
  const int wg   = lane & 15;            // w-group within row (16 x float4 = row)
  const int hs   = lane >> 4;            // h-sub within wave
  const int w0   = wg * 4;
  const int h    = blockIdx.x * HT + threadIdx.y * 4 + hs;
  const int d0   = blockIdx.y * DC;
  const int b    = blockIdx.z;

  const size_t plane = (size_t)HDIM * WWID;   // 16384 floats
  const float* src = in  + (size_t)b * DDIM * plane;
  float*       dst = out + (size_t)b * DDIM * plane;

  const size_t offb = (size_t)h * WWID + w0;  // this thread's row base
  const bool va = (h > 0);                    // h-1 valid (per-thread constant)
  const bool vc = (h + 1 < HDIM);             // h+1 valid

  auto loadPlane = [&](int d, float4& ra, float4& rb, float4& rc) {
    if ((unsigned)d < (unsigned)DDIM) {
      const float* p = src + (size_t)d * plane;
      rb = *(const float4*)(p + offb);
      ra = va ? *(const float4*)(p + offb - WWID) : float4{0.f, 0.f, 0.f, 0.f};
      rc = vc ? *(const float4*)(p + offb + WWID) : float4{0.f, 0.f, 0.f, 0.f};
    } else {
      ra = rb = rc = float4{0.f, 0.f, 0.f, 0.f};
    }
  };

  // row partials S (1,2,1) and D (1,0,-1) at the 4 output w positions
  auto rowSD = [&](float4 v, float* S, float* D) {
    const float x1 = (v.x == 255.f) ? 0.f : v.x;   // reference where()
    const float x2 = (v.y == 255.f) ? 0.f : v.y;
    const float x3 = (v.z == 255.f) ? 0.f : v.z;
    const float x4 = (v.w == 255.f) ? 0.f : v.w;
    const float xm = dpp_up1(x4);   // x[w0-1] (0 at w-edge)
    const float xp = dpp_dn1(x1);   // x[w0+4] (0 at w-edge)
    const float x[6] = {xm, x1, x2, x3, x4, xp};
    #pragma unroll
    for (int i = 0; i < 4; ++i) {
      S[i] = fmaf(2.f, x[i + 1], x[i]) + x[i + 2];
      D[i] = x[i] - x[i + 2];
    }
  };

  auto partials = [&](const float4& ra, const float4& rb, const float4& rc, P3& o) {
    float Sa[4], Da[4], Sb[4], Db[4], Sc[4], Dc[4];
    rowSD(ra, Sa, Da);
    rowSD(rb, Sb, Db);
    rowSD(rc, Sc, Dc);
    #pragma unroll
    for (int i = 0; i < 4; ++i) {
      o.ds[i] = Da[i] + Db[i] + Dc[i];
      o.ss[i] = Sa[i] + Sb[i] + Sc[i];
      o.sd[i] = Sa[i] - Sc[i];
    }
  };

  auto emit = [&](int d, const P3& p, const P3& c, const P3& n) {
    float4 o;
    #pragma unroll
    for (int i = 0; i < 4; ++i) {
      const float Gx = fmaf(2.f, c.ds[i], p.ds[i]) + n.ds[i];
      const float Gy = p.ss[i] - n.ss[i];
      const float Gz = p.sd[i] + c.sd[i] + n.sd[i];
      const int cnt = (Gx != 0.f) + (Gy != 0.f) + (Gz != 0.f);
      (&o.x)[i] = (cnt >= 2) ? 1.f : 0.f;
    }
    *(float4*)(dst + (size_t)d * plane + offb) = o;
  };

  float4 A0, B0, C0, A1, B1, C1, A2, B2, C2;   // 3-plane raw ring
  P3 p0, p1, p2;

  // fully unrolled 2-deep pipeline over planes d0-1 .. d0+4 (6 loads, 4 outputs)
  loadPlane(d0 - 1, A0, B0, C0);
  loadPlane(d0,     A1, B1, C1);
  loadPlane(d0 + 1, A2, B2, C2);
  partials(A0, B0, C0, p0);  loadPlane(d0 + 2, A0, B0, C0);
  partials(A1, B1, C1, p1);  loadPlane(d0 + 3, A1, B1, C1);
  partials(A2, B2, C2, p2);  loadPlane(d0 + 4, A2, B2, C2);
  emit(d0,     p0, p1, p2);
  partials(A0, B0, C0, p0);                 // plane d0+2
  emit(d0 + 1, p1, p2, p0);
  partials(A1, B1, C1, p1);                 // plane d0+3
  emit(d0 + 2, p2, p0, p1);
  partials(A2, B2, C2, p2);                 // plane d0+4
  emit(d0 + 3, p0, p1, p2);
}

extern "C" void kernel_launch(void* const* d_in, const int* in_sizes, int n_in,
                              void* d_out, int out_size, void* d_ws, size_t ws_size,
                              hipStream_t stream) {
  const float* data = (const float*)d_in[0];
  // d_in[1] = Sobel weights — fixed by the reference, folded into the kernel.
  float* out = (float*)d_out;
  dim3 grid(HDIM / HT, DDIM / DC, 4);   // (32, 64, 4) = 8192 blocks
  dim3 block(WWID, 2);                  // 128 threads = 2 waves
  sobel3d_kernel<<<grid, block, 0, stream>>>(data, out);
}